// Round 7
// baseline (990.565 us; speedup 1.0000x reference)
//
#include <hip/hip_runtime.h>

// SparseLayer: out[n] = ((self[n] + sum_j neigh[n*32+j]) / 33) @ W + bias
// N=50000, NEIGH=32, D=128, fp32.
//
// R7 = R6 + occupancy push: launch_bounds(256,8) targets <=64 VGPR ->
// 8 waves/SIMD = 32 waves/CU (R6 was 24). Phase-2 W sweep restructured to
// 2-row groups to fit the register cap. Structure otherwise identical to R6.

typedef float f32x4 __attribute__((ext_vector_type(4)));

constexpr int D       = 128;
constexpr int D4      = D / 4;            // 32
constexpr int NEIGH   = 32;
constexpr int WAVES   = 4;
constexpr int THREADS = WAVES * 64;       // 256
constexpr int NPW     = 4;                // nodes per wave
constexpr int NPB     = WAVES * NPW;      // 16 nodes per block -> 3125 blocks exact

__global__ __launch_bounds__(THREADS, 8)  // 8 waves/SIMD target (<=64 VGPR)
void sparse_layer_v5(const float* __restrict__ self_vecs,
                     const float* __restrict__ neigh_vecs,
                     const float* __restrict__ weight,
                     const float* __restrict__ bias,
                     float* __restrict__ out, int n_nodes)
{
    __shared__ float agg_lds[WAVES][NPW][D];   // 8 KiB

    const int wave = threadIdx.x >> 6;
    const int lane = threadIdx.x & 63;
    const int h    = lane >> 5;            // half: even/odd rows, low/high k
    const int c4   = lane & 31;            // float4 column

    const f32x4* s4 = reinterpret_cast<const f32x4*>(self_vecs);
    const f32x4* g4 = reinterpret_cast<const f32x4*>(neigh_vecs);
    const f32x4* w4 = reinterpret_cast<const f32x4*>(weight);
    constexpr float inv = 1.0f / (NEIGH + 1);

    const long base = (long)blockIdx.x * NPB + wave * NPW;

    // ---- phase 1: aggregate 4 nodes (16 linear 1-KB wave-loads each) ----
    #pragma unroll
    for (int i = 0; i < NPW; ++i) {
        const long n = base + i;
        if (n >= n_nodes) break;           // wave-uniform (never taken at N=50000)
        const f32x4* p = g4 + n * (long)NEIGH * D4;
        f32x4 acc = (f32x4)0.0f;
        if (h == 0) acc = __builtin_nontemporal_load(&s4[n * D4 + c4]);
        #pragma unroll 8
        for (int l = 0; l < 16; ++l)
            acc += __builtin_nontemporal_load(&p[l * 64 + lane]);  // row 2l+h
        f32x4 tot;
        tot.x = acc.x + __shfl_xor(acc.x, 32);
        tot.y = acc.y + __shfl_xor(acc.y, 32);
        tot.z = acc.z + __shfl_xor(acc.z, 32);
        tot.w = acc.w + __shfl_xor(acc.w, 32);
        if (h == 0)
            reinterpret_cast<f32x4*>(agg_lds[wave][i])[c4] = tot * inv;
    }

    // ---- phase 2: one W sweep (L1/L2) computes all 4 nodes, 2-row groups ----
    f32x4 o0 = (f32x4)0.0f, o1 = (f32x4)0.0f, o2 = (f32x4)0.0f, o3 = (f32x4)0.0f;
    const f32x4* a0 = reinterpret_cast<const f32x4*>(agg_lds[wave][0]);
    const f32x4* a1 = reinterpret_cast<const f32x4*>(agg_lds[wave][1]);
    const f32x4* a2 = reinterpret_cast<const f32x4*>(agg_lds[wave][2]);
    const f32x4* a3 = reinterpret_cast<const f32x4*>(agg_lds[wave][3]);

    for (int k4 = 0; k4 < D4 / 2; ++k4) {
        const int kk = h * (D4 / 2) + k4;         // h-split k range
        f32x4 b0 = a0[kk];                        // LDS broadcast within half
        f32x4 b1 = a1[kk];
        f32x4 b2 = a2[kk];
        f32x4 b3 = a3[kk];
        {
            f32x4 w0 = w4[(4 * kk + 0) * D4 + c4];
            f32x4 w1 = w4[(4 * kk + 1) * D4 + c4];
            o0 += b0.x * w0;  o0 += b0.y * w1;
            o1 += b1.x * w0;  o1 += b1.y * w1;
            o2 += b2.x * w0;  o2 += b2.y * w1;
            o3 += b3.x * w0;  o3 += b3.y * w1;
        }
        {
            f32x4 w2 = w4[(4 * kk + 2) * D4 + c4];
            f32x4 w3 = w4[(4 * kk + 3) * D4 + c4];
            o0 += b0.z * w2;  o0 += b0.w * w3;
            o1 += b1.z * w2;  o1 += b1.w * w3;
            o2 += b2.z * w2;  o2 += b2.w * w3;
            o3 += b3.z * w2;  o3 += b3.w * w3;
        }
    }

    // cross-half merge + write
    const f32x4 bv = reinterpret_cast<const f32x4*>(bias)[c4];
    f32x4* o4 = reinterpret_cast<f32x4*>(out);
    f32x4 oo[NPW] = {o0, o1, o2, o3};
    #pragma unroll
    for (int i = 0; i < NPW; ++i) {
        f32x4 o = oo[i];
        o.x += __shfl_xor(o.x, 32);
        o.y += __shfl_xor(o.y, 32);
        o.z += __shfl_xor(o.z, 32);
        o.w += __shfl_xor(o.w, 32);
        const long n = base + i;
        if (h == 0 && n < n_nodes)
            __builtin_nontemporal_store(o + bv, &o4[n * D4 + c4]);
    }
}

extern "C" void kernel_launch(void* const* d_in, const int* in_sizes, int n_in,
                              void* d_out, int out_size, void* d_ws, size_t ws_size,
                              hipStream_t stream) {
    const float* self_vecs  = (const float*)d_in[0];
    const float* neigh_vecs = (const float*)d_in[1];
    // d_in[2] = neigh_num (==32, compile-time NEIGH)
    const float* weight     = (const float*)d_in[3];
    const float* bias       = (const float*)d_in[4];
    float*       out        = (float*)d_out;

    const int n_nodes = in_sizes[0] / D;                 // 50000
    const int blocks  = (n_nodes + NPB - 1) / NPB;       // 3125 exact
    hipLaunchKernelGGL(sparse_layer_v5, dim3(blocks), dim3(THREADS), 0, stream,
                       self_vecs, neigh_vecs, weight, bias, out, n_nodes);
}

// Round 8
// 869.388 us; speedup vs baseline: 1.1394x; 1.1394x over previous
//
#include <hip/hip_runtime.h>

// SparseLayer: out[n] = ((self[n] + sum_j neigh[n*32+j]) / 33) @ W + bias
// N=50000, NEIGH=32, D=128, fp32.
//
// R8 = R6 structure at NPW=2 to shrink the natural VGPR footprint (~55) so
// launch_bounds(256,8) (budget 64 VGPR -> 32 waves/CU) is met WITHOUT spills
// (R7 forced 8 waves on ~85-VGPR code -> spill catastrophe, 2.2 GB scratch
// traffic). W stays in L1/L2 (not LDS); agg rows wave-private in LDS; no
// barriers; no register arrays.

typedef float f32x4 __attribute__((ext_vector_type(4)));

constexpr int D       = 128;
constexpr int D4      = D / 4;            // 32
constexpr int NEIGH   = 32;
constexpr int WAVES   = 4;
constexpr int THREADS = WAVES * 64;       // 256
constexpr int NPW     = 2;                // nodes per wave
constexpr int NPB     = WAVES * NPW;      // 8 nodes per block -> 6250 blocks exact

__global__ __launch_bounds__(THREADS, 8)  // 8 blocks/CU = 32 waves/CU, 64 VGPR budget
void sparse_layer_v6(const float* __restrict__ self_vecs,
                     const float* __restrict__ neigh_vecs,
                     const float* __restrict__ weight,
                     const float* __restrict__ bias,
                     float* __restrict__ out, int n_nodes)
{
    __shared__ float agg_lds[WAVES][NPW][D];   // 4 KiB

    const int wave = threadIdx.x >> 6;
    const int lane = threadIdx.x & 63;
    const int h    = lane >> 5;            // half: even/odd rows, low/high k
    const int c4   = lane & 31;            // float4 column

    const f32x4* s4 = reinterpret_cast<const f32x4*>(self_vecs);
    const f32x4* g4 = reinterpret_cast<const f32x4*>(neigh_vecs);
    const f32x4* w4 = reinterpret_cast<const f32x4*>(weight);
    constexpr float inv = 1.0f / (NEIGH + 1);

    const long base = (long)blockIdx.x * NPB + wave * NPW;

    // ---- phase 1: aggregate 2 nodes (16 linear 1-KB wave-loads each) ----
    #pragma unroll
    for (int i = 0; i < NPW; ++i) {
        const long n = base + i;
        if (n >= n_nodes) break;           // wave-uniform (never taken: 50000%8==0)
        const f32x4* p = g4 + n * (long)NEIGH * D4;
        f32x4 acc = (f32x4)0.0f;
        if (h == 0) acc = __builtin_nontemporal_load(&s4[n * D4 + c4]);
        #pragma unroll 4
        for (int l = 0; l < 16; ++l)
            acc += __builtin_nontemporal_load(&p[l * 64 + lane]);  // row 2l+h
        f32x4 tot;
        tot.x = acc.x + __shfl_xor(acc.x, 32);
        tot.y = acc.y + __shfl_xor(acc.y, 32);
        tot.z = acc.z + __shfl_xor(acc.z, 32);
        tot.w = acc.w + __shfl_xor(acc.w, 32);
        if (h == 0)
            reinterpret_cast<f32x4*>(agg_lds[wave][i])[c4] = tot * inv;
    }

    // ---- phase 2: one W sweep (L1/L2) computes both nodes, 2-row groups ----
    f32x4 o0 = (f32x4)0.0f, o1 = (f32x4)0.0f;
    const f32x4* a0 = reinterpret_cast<const f32x4*>(agg_lds[wave][0]);
    const f32x4* a1 = reinterpret_cast<const f32x4*>(agg_lds[wave][1]);

    for (int k4 = 0; k4 < D4 / 2; ++k4) {
        const int kk = h * (D4 / 2) + k4;         // h-split k range
        f32x4 b0 = a0[kk];                        // LDS broadcast within half
        f32x4 b1 = a1[kk];
        {
            f32x4 w0 = w4[(4 * kk + 0) * D4 + c4];
            f32x4 w1 = w4[(4 * kk + 1) * D4 + c4];
            o0 += b0.x * w0;  o0 += b0.y * w1;
            o1 += b1.x * w0;  o1 += b1.y * w1;
        }
        {
            f32x4 w2 = w4[(4 * kk + 2) * D4 + c4];
            f32x4 w3 = w4[(4 * kk + 3) * D4 + c4];
            o0 += b0.z * w2;  o0 += b0.w * w3;
            o1 += b1.z * w2;  o1 += b1.w * w3;
        }
    }

    // ---- cross-half merge + write (no register arrays) ----
    const f32x4 bv = reinterpret_cast<const f32x4*>(bias)[c4];
    f32x4* o4 = reinterpret_cast<f32x4*>(out);

    o0.x += __shfl_xor(o0.x, 32);
    o0.y += __shfl_xor(o0.y, 32);
    o0.z += __shfl_xor(o0.z, 32);
    o0.w += __shfl_xor(o0.w, 32);
    if (h == 0 && base < n_nodes)
        __builtin_nontemporal_store(o0 + bv, &o4[base * D4 + c4]);

    o1.x += __shfl_xor(o1.x, 32);
    o1.y += __shfl_xor(o1.y, 32);
    o1.z += __shfl_xor(o1.z, 32);
    o1.w += __shfl_xor(o1.w, 32);
    if (h == 0 && base + 1 < n_nodes)
        __builtin_nontemporal_store(o1 + bv, &o4[(base + 1) * D4 + c4]);
}

extern "C" void kernel_launch(void* const* d_in, const int* in_sizes, int n_in,
                              void* d_out, int out_size, void* d_ws, size_t ws_size,
                              hipStream_t stream) {
    const float* self_vecs  = (const float*)d_in[0];
    const float* neigh_vecs = (const float*)d_in[1];
    // d_in[2] = neigh_num (==32, compile-time NEIGH)
    const float* weight     = (const float*)d_in[3];
    const float* bias       = (const float*)d_in[4];
    float*       out        = (float*)d_out;

    const int n_nodes = in_sizes[0] / D;                 // 50000
    const int blocks  = (n_nodes + NPB - 1) / NPB;       // 6250 exact
    hipLaunchKernelGGL(sparse_layer_v6, dim3(blocks), dim3(THREADS), 0, stream,
                       self_vecs, neigh_vecs, weight, bias, out, n_nodes);
}

// Round 9
// 160.172 us; speedup vs baseline: 6.1844x; 5.4279x over previous
//
#include <hip/hip_runtime.h>

// SparseLayer: out[n] = ((self[n] + sum_j neigh[n*32+j]) / 33) @ W + bias
// N=50000, NEIGH=32, D=128, fp32.
//
// R9 = R6 verbatim (best verified: 160.2 us, 5.44 TB/s).
// Design record:
//  - 16 waves/CU (W in LDS)          -> 5.02 TB/s (173 us)
//  - 24 waves/CU (W via L1/L2, this) -> 5.44 TB/s (160 us)
//  - 32 waves/CU (launch_bounds .,8) -> compiler caps at 32 VGPR, spills,
//    2+ GB scratch traffic, 869-1028 us. Do NOT raise the bound.
// Barrier placement / stream microstructure / pipelining: all +-3% neutral
// (R1-R5). This point is ~86% of the 6.29 TB/s copy ceiling on a 97%-read
// stream; remaining gap is read-path latency at 24 waves/CU.

typedef float f32x4 __attribute__((ext_vector_type(4)));

constexpr int D       = 128;
constexpr int D4      = D / 4;            // 32
constexpr int NEIGH   = 32;
constexpr int WAVES   = 4;
constexpr int THREADS = WAVES * 64;       // 256
constexpr int NPW     = 4;                // nodes per wave
constexpr int NPB     = WAVES * NPW;      // 16 nodes per block -> 3125 blocks exact

__global__ __launch_bounds__(THREADS, 6)  // 6 waves/SIMD = 24 waves/CU; no spills
void sparse_layer_v4(const float* __restrict__ self_vecs,
                     const float* __restrict__ neigh_vecs,
                     const float* __restrict__ weight,
                     const float* __restrict__ bias,
                     float* __restrict__ out, int n_nodes)
{
    __shared__ float agg_lds[WAVES][NPW][D];   // 8 KiB

    const int wave = threadIdx.x >> 6;
    const int lane = threadIdx.x & 63;
    const int h    = lane >> 5;            // half: even/odd rows, low/high k
    const int c4   = lane & 31;            // float4 column

    const f32x4* s4 = reinterpret_cast<const f32x4*>(self_vecs);
    const f32x4* g4 = reinterpret_cast<const f32x4*>(neigh_vecs);
    const f32x4* w4 = reinterpret_cast<const f32x4*>(weight);
    constexpr float inv = 1.0f / (NEIGH + 1);

    const long base = (long)blockIdx.x * NPB + wave * NPW;

    // ---- phase 1: aggregate 4 nodes (16 linear 1-KB wave-loads each) ----
    #pragma unroll
    for (int i = 0; i < NPW; ++i) {
        const long n = base + i;
        if (n >= n_nodes) break;           // wave-uniform (never taken at N=50000)
        const f32x4* p = g4 + n * (long)NEIGH * D4;
        f32x4 acc = (f32x4)0.0f;
        if (h == 0) acc = __builtin_nontemporal_load(&s4[n * D4 + c4]);
        #pragma unroll 8
        for (int l = 0; l < 16; ++l)
            acc += __builtin_nontemporal_load(&p[l * 64 + lane]);  // row 2l+h
        f32x4 tot;
        tot.x = acc.x + __shfl_xor(acc.x, 32);
        tot.y = acc.y + __shfl_xor(acc.y, 32);
        tot.z = acc.z + __shfl_xor(acc.z, 32);
        tot.w = acc.w + __shfl_xor(acc.w, 32);
        if (h == 0)
            reinterpret_cast<f32x4*>(agg_lds[wave][i])[c4] = tot * inv;
    }

    // ---- phase 2: one W sweep (global/L2) computes all 4 nodes ----
    f32x4 o0 = (f32x4)0.0f, o1 = (f32x4)0.0f, o2 = (f32x4)0.0f, o3 = (f32x4)0.0f;
    const f32x4* a0 = reinterpret_cast<const f32x4*>(agg_lds[wave][0]);
    const f32x4* a1 = reinterpret_cast<const f32x4*>(agg_lds[wave][1]);
    const f32x4* a2 = reinterpret_cast<const f32x4*>(agg_lds[wave][2]);
    const f32x4* a3 = reinterpret_cast<const f32x4*>(agg_lds[wave][3]);

    #pragma unroll 4
    for (int k4 = 0; k4 < D4 / 2; ++k4) {
        const int kk = h * (D4 / 2) + k4;         // h-split k range
        f32x4 w0 = w4[(4 * kk + 0) * D4 + c4];    // L1/L2-resident, coalesced
        f32x4 w1 = w4[(4 * kk + 1) * D4 + c4];
        f32x4 w2 = w4[(4 * kk + 2) * D4 + c4];
        f32x4 w3 = w4[(4 * kk + 3) * D4 + c4];
        f32x4 b0 = a0[kk];                        // LDS broadcast within half
        f32x4 b1 = a1[kk];
        f32x4 b2 = a2[kk];
        f32x4 b3 = a3[kk];
        o0 += b0.x * w0;  o0 += b0.y * w1;  o0 += b0.z * w2;  o0 += b0.w * w3;
        o1 += b1.x * w0;  o1 += b1.y * w1;  o1 += b1.z * w2;  o1 += b1.w * w3;
        o2 += b2.x * w0;  o2 += b2.y * w1;  o2 += b2.z * w2;  o2 += b2.w * w3;
        o3 += b3.x * w0;  o3 += b3.y * w1;  o3 += b3.z * w2;  o3 += b3.w * w3;
    }

    // cross-half merge + write
    const f32x4 bv = reinterpret_cast<const f32x4*>(bias)[c4];
    f32x4* o4 = reinterpret_cast<f32x4*>(out);
    f32x4 oo[NPW] = {o0, o1, o2, o3};
    #pragma unroll
    for (int i = 0; i < NPW; ++i) {
        f32x4 o = oo[i];
        o.x += __shfl_xor(o.x, 32);
        o.y += __shfl_xor(o.y, 32);
        o.z += __shfl_xor(o.z, 32);
        o.w += __shfl_xor(o.w, 32);
        const long n = base + i;
        if (h == 0 && n < n_nodes)
            __builtin_nontemporal_store(o + bv, &o4[n * D4 + c4]);
    }
}

extern "C" void kernel_launch(void* const* d_in, const int* in_sizes, int n_in,
                              void* d_out, int out_size, void* d_ws, size_t ws_size,
                              hipStream_t stream) {
    const float* self_vecs  = (const float*)d_in[0];
    const float* neigh_vecs = (const float*)d_in[1];
    // d_in[2] = neigh_num (==32, compile-time NEIGH)
    const float* weight     = (const float*)d_in[3];
    const float* bias       = (const float*)d_in[4];
    float*       out        = (float*)d_out;

    const int n_nodes = in_sizes[0] / D;                 // 50000
    const int blocks  = (n_nodes + NPB - 1) / NPB;       // 3125 exact
    hipLaunchKernelGGL(sparse_layer_v4, dim3(blocks), dim3(THREADS), 0, stream,
                       self_vecs, neigh_vecs, weight, bias, out, n_nodes);
}